// Round 6
// baseline (185.231 us; speedup 1.0000x reference)
//
#include <hip/hip_runtime.h>
#include <stdint.h>

typedef __bf16 bf16x8 __attribute__((ext_vector_type(8)));
typedef float f32x4 __attribute__((ext_vector_type(4)));
typedef float f32x2 __attribute__((ext_vector_type(2)));
typedef unsigned short u16x4 __attribute__((ext_vector_type(4)));
typedef unsigned short u16x8 __attribute__((ext_vector_type(8)));

#define NTOK 20000
#define HIW  256
#define HD   2048
#define LDK  66   // shorts; 33 dwords (odd) -> conflict-free b64 writes / uniform b128 reads

static __device__ __forceinline__ unsigned short f2bf(float f) {
  union { float f; unsigned u; } c; c.f = f;
  unsigned u = c.u + (0x7fffu + ((c.u >> 16) & 1u));   // RNE
  return (unsigned short)(u >> 16);
}
static __device__ __forceinline__ float bf2f(unsigned short h) {
  union { unsigned u; float f; } c; c.u = ((unsigned)h) << 16;
  return c.f;
}

#define WRED(x) { x += __shfl_xor(x,32); x += __shfl_xor(x,16); x += __shfl_xor(x,8); \
                  x += __shfl_xor(x,4);  x += __shfl_xor(x,2);  x += __shfl_xor(x,1); }

// ============ k_front: [0,256) k_s | [256,384) k_pc (pair-split) | 384 lambda ============
// scal: 0=lam 1=-lam 2=1-li 3=li 4=dc 5=alpha_c 6=css 7=cbar
__global__ __launch_bounds__(256) void k_front(
    const float* __restrict__ kk, const float* __restrict__ vv,
    const float* __restrict__ Wq1, const float* __restrict__ Wk1,
    const float* __restrict__ Wq2, const float* __restrict__ Wk2,
    const float* __restrict__ lq1, const float* __restrict__ lk1,
    const float* __restrict__ lq2, const float* __restrict__ lk2,
    const float* __restrict__ bq1, const float* __restrict__ bk1,
    const float* __restrict__ bq2, const float* __restrict__ bk2,
    const int* __restrict__ layer,
    float* __restrict__ S_part, float* __restrict__ skp, float* __restrict__ svp,
    float* __restrict__ Pc_part, float* __restrict__ scal) {
  __shared__ unsigned short SH[2 * 128 * LDK];   // 33792 B -> 4 blocks/CU
  unsigned short* Ak = SH;
  unsigned short* Bk = SH + 128 * LDK;
  const int b = blockIdx.x;
  const int t = threadIdx.x, lane = t & 63, wave = t >> 6;
  const int wr = (wave >> 1) * 64, wc = (wave & 1) * 64;
  const int r15 = lane & 15, kg = (lane >> 4) * 8;

  if (b < 256) {
    // ----- S_part[z] = k^T v over n-chunk z (bf16, transpose-staged) -----
    const int z = b & 63, by = (b >> 6) & 1, bx = (b >> 7) & 1;
    const int i0 = bx * 128, j0 = by * 128;
    const int n_lo = z * 313;
    const int cnt = (NTOK - n_lo < 313) ? (NTOK - n_lo) : 313;
    f32x4 acc[4][4];
    #pragma unroll
    for (int m = 0; m < 4; ++m)
      #pragma unroll
      for (int n = 0; n < 4; ++n) acc[m][n] = (f32x4){0.f, 0.f, 0.f, 0.f};

    const int col = t & 127;            // tile-local column this thread stages
    const int matsel = t >> 7;          // 0: k-tile, 1: v-tile
    const float* src = matsel ? vv : kk;
    const int gcol = (matsel ? j0 : i0) + col;
    unsigned short* Ldst = matsel ? Bk : Ak;
    float csum = 0.f;

    for (int kt = 0; kt < 5; ++kt) {
      __syncthreads();
      #pragma unroll
      for (int g = 0; g < 16; ++g) {
        const int tokb = kt * 64 + g * 4;
        f32x4 vals;
        #pragma unroll
        for (int jj = 0; jj < 4; ++jj) {
          const int nn = tokb + jj;
          vals[jj] = (nn < cnt) ? src[(size_t)(n_lo + nn) * HIW + gcol] : 0.f;
        }
        csum += (vals[0] + vals[1]) + (vals[2] + vals[3]);
        u16x4 o;
        #pragma unroll
        for (int jj = 0; jj < 4; ++jj) o[jj] = f2bf(vals[jj]);
        *(u16x4*)&Ldst[col * LDK + g * 4] = o;   // conflict-free b64
      }
      __syncthreads();
      #pragma unroll
      for (int ks = 0; ks < 2; ++ks) {
        const int ko = ks * 32 + kg;
        bf16x8 ah[4], bh[4];
        #pragma unroll
        for (int m = 0; m < 4; ++m)
          ah[m] = *(const bf16x8*)&Ak[(wr + m * 16 + r15) * LDK + ko];
        #pragma unroll
        for (int n = 0; n < 4; ++n)
          bh[n] = *(const bf16x8*)&Bk[(wc + n * 16 + r15) * LDK + ko];
        #pragma unroll
        for (int m = 0; m < 4; ++m)
          #pragma unroll
          for (int n = 0; n < 4; ++n)
            acc[m][n] = __builtin_amdgcn_mfma_f32_16x16x32_bf16(ah[m], bh[n], acc[m][n], 0, 0, 0);
      }
    }
    const int rg = (lane >> 4) * 4;
    #pragma unroll
    for (int m = 0; m < 4; ++m)
      #pragma unroll
      for (int n = 0; n < 4; ++n)
        #pragma unroll
        for (int r = 0; r < 4; ++r)
          S_part[(size_t)z * 65536 + (i0 + wr + m * 16 + rg + r) * 256 + (j0 + wc + n * 16 + r15)] =
              acc[m][n][r];
    if (bx == by) {   // diagonal blocks own the column sums (each col by one thread)
      if (matsel == 0) skp[z * 256 + gcol] = csum;
      else             svp[z * 256 + gcol] = csum;
    }
  } else if (b < 384) {
    // ----- Pc_part[pair*16+z] = Wa Wb^T K-slice (bf16, unscaled) -----
    const int idx = b - 256;
    const int pair = idx >> 6, rem = idx & 63;
    const int z = rem & 15, by = (rem >> 4) & 1, bx = (rem >> 5) & 1;
    const int i0 = bx * 128, j0 = by * 128;
    const float* Wa = pair ? Wq2 : Wq1;
    const float* Wb = pair ? Wk2 : Wk1;
    f32x4 acc[4][4];
    #pragma unroll
    for (int m = 0; m < 4; ++m)
      #pragma unroll
      for (int n = 0; n < 4; ++n) acc[m][n] = (f32x4){0.f, 0.f, 0.f, 0.f};
    const int srow = t >> 1, sh = (t & 1) * 32;
    for (int kt = 0; kt < 2; ++kt) {
      const int kb = z * 128 + kt * 64 + sh;
      __syncthreads();
      #pragma unroll
      for (int c = 0; c < 8; ++c) {
        f32x4 a = *(const f32x4*)&Wa[(size_t)(i0 + srow) * HD + kb + c * 4];
        f32x4 bb = *(const f32x4*)&Wb[(size_t)(j0 + srow) * HD + kb + c * 4];
        u16x4 oa, ob;
        #pragma unroll
        for (int u = 0; u < 4; ++u) { oa[u] = f2bf(a[u]); ob[u] = f2bf(bb[u]); }
        *(u16x4*)&Ak[srow * LDK + sh + c * 4] = oa;
        *(u16x4*)&Bk[srow * LDK + sh + c * 4] = ob;
      }
      __syncthreads();
      #pragma unroll
      for (int ks = 0; ks < 2; ++ks) {
        const int ko = ks * 32 + kg;
        bf16x8 ah[4], bh[4];
        #pragma unroll
        for (int m = 0; m < 4; ++m)
          ah[m] = *(const bf16x8*)&Ak[(wr + m * 16 + r15) * LDK + ko];
        #pragma unroll
        for (int n = 0; n < 4; ++n)
          bh[n] = *(const bf16x8*)&Bk[(wc + n * 16 + r15) * LDK + ko];
        #pragma unroll
        for (int m = 0; m < 4; ++m)
          #pragma unroll
          for (int n = 0; n < 4; ++n)
            acc[m][n] = __builtin_amdgcn_mfma_f32_16x16x32_bf16(ah[m], bh[n], acc[m][n], 0, 0, 0);
      }
    }
    const int rg = (lane >> 4) * 4;
    #pragma unroll
    for (int m = 0; m < 4; ++m)
      #pragma unroll
      for (int n = 0; n < 4; ++n)
        #pragma unroll
        for (int r = 0; r < 4; ++r)
          Pc_part[(size_t)(pair * 16 + z) * 65536 +
                  (i0 + wr + m * 16 + rg + r) * 256 + (j0 + wc + n * 16 + r15)] = acc[m][n][r];
  } else {
    // ----- lambda scalars -----
    float p1 = lq1[t] * lk1[t], p2 = lq2[t] * lk2[t];
    float d1 = 0.f, d2 = 0.f;
    #pragma unroll
    for (int u = 0; u < 8; ++u) {
      d1 += bq1[t * 8 + u] * bk1[t * 8 + u];
      d2 += bq2[t * 8 + u] * bk2[t * 8 + u];
    }
    WRED(p1); WRED(p2); WRED(d1); WRED(d2);
    float* red = (float*)SH;
    int w = t >> 6;
    if ((t & 63) == 0) { red[w] = p1; red[4 + w] = p2; red[8 + w] = d1; red[12 + w] = d2; }
    __syncthreads();
    if (t == 0) {
      float s1 = red[0] + red[1] + red[2] + red[3];
      float s2 = red[4] + red[5] + red[6] + red[7];
      float dd1 = red[8] + red[9] + red[10] + red[11];
      float dd2 = red[12] + red[13] + red[14] + red[15];
      float li = 0.8f - 0.6f * expf(-0.3f * (float)layer[0]);
      float lam = expf(s1) - expf(s2) + li;
      scal[0] = lam; scal[1] = -lam; scal[2] = 1.0f - li; scal[3] = li;
      scal[4] = dd1 - lam * dd2;
    }
  }
}

// reductions + gc/uc matvecs
__global__ __launch_bounds__(256) void k_sred(
    const float* __restrict__ S_part, const float* __restrict__ Pc_part,
    const float* __restrict__ skp, const float* __restrict__ svp,
    float* __restrict__ S, float* __restrict__ Pc,
    float* __restrict__ sk, float* __restrict__ sv,
    const float* __restrict__ Wk1, const float* __restrict__ Wk2,
    const float* __restrict__ Wq1, const float* __restrict__ Wq2,
    const float* __restrict__ bq1, const float* __restrict__ bq2,
    const float* __restrict__ bk1, const float* __restrict__ bk2,
    const float* __restrict__ scal, float* __restrict__ gc, float* __restrict__ uc) {
  int b = blockIdx.x, t = threadIdx.x;
  if (b < 256) {
    int idx = b * 256 + t;
    float s = 0.f;
    for (int z = 0; z < 64; ++z) s += S_part[(size_t)z * 65536 + idx];
    S[idx] = s;
  } else if (b < 512) {
    int idx = (b - 256) * 256 + t;
    float s1 = 0.f, s2 = 0.f;
    #pragma unroll
    for (int z = 0; z < 16; ++z) {
      s1 += Pc_part[(size_t)z * 65536 + idx];
      s2 += Pc_part[(size_t)(16 + z) * 65536 + idx];
    }
    Pc[idx] = s1 - scal[0] * s2;
  } else if (b < 514) {
    const float* src = (b == 512) ? skp : svp;
    float s = 0.f;
    for (int z = 0; z < 64; ++z) s += src[z * 256 + t];
    if (b == 512) sk[t] = s; else sv[t] = s;
  } else {
    int bb = b - 514, lane = t & 63, w = t >> 6;
    bool dogc = bb < 16;
    const float* A1 = dogc ? Wk1 : Wq1;
    const float* A2 = dogc ? Wk2 : Wq2;
    const float* x1 = dogc ? bq1 : bk1;
    const float* x2 = dogc ? bq2 : bk2;
    float* outv = dogc ? gc : uc;
    float lam = scal[0];
    int rb = (bb & 15) * 16 + w * 4;
    for (int q2 = 0; q2 < 4; ++q2) {
      int row = rb + q2;
      float s1 = 0.f, s2 = 0.f;
      #pragma unroll
      for (int c = 0; c < 8; ++c) {
        int kk2 = c * 256 + lane * 4;
        f32x4 a1 = *(const f32x4*)&A1[(size_t)row * HD + kk2];
        f32x4 a2 = *(const f32x4*)&A2[(size_t)row * HD + kk2];
        f32x4 v1 = *(const f32x4*)&x1[kk2];
        f32x4 v2 = *(const f32x4*)&x2[kk2];
        #pragma unroll
        for (int u = 0; u < 4; ++u) { s1 += a1[u] * v1[u]; s2 += a2[u] * v2[u]; }
      }
      WRED(s1); WRED(s2);
      if (lane == 0) outv[row] = s1 - lam * s2;
    }
  }
}

// Ac = Pc @ S ; tc = Pc @ sk ; rv = S^T gc ; alpha_c = gc . sk
__global__ __launch_bounds__(256) void k_ac(
    const float* __restrict__ Pc, const float* __restrict__ S,
    const float* __restrict__ gc, const float* __restrict__ sk,
    float* __restrict__ Ac, float* __restrict__ tc, float* __restrict__ rv,
    float* __restrict__ scal) {
  int b = blockIdx.x, t = threadIdx.x;
  if (b < 32) {
    __shared__ float Pt[32][68];
    __shared__ float St[64][68];
    int i0 = (b >> 2) * 32, j0 = (b & 3) * 64;
    int ti = t >> 5, tj = t & 31;
    float acc[4][2] = {};
    for (int kt = 0; kt < 256; kt += 64) {
      __syncthreads();
      {
        int rr = t >> 3, c8 = (t & 7) * 8;
        *(f32x4*)&Pt[rr][c8] = *(const f32x4*)&Pc[(i0 + rr) * 256 + kt + c8];
        *(f32x4*)&Pt[rr][c8 + 4] = *(const f32x4*)&Pc[(i0 + rr) * 256 + kt + c8 + 4];
      }
      {
        int rr = t >> 2, c16 = (t & 3) * 16;
        #pragma unroll
        for (int c = 0; c < 4; ++c)
          *(f32x4*)&St[rr][c16 + c * 4] = *(const f32x4*)&S[(kt + rr) * 256 + j0 + c16 + c * 4];
      }
      __syncthreads();
      #pragma unroll 8
      for (int k2 = 0; k2 < 64; ++k2) {
        float a[4];
        #pragma unroll
        for (int u = 0; u < 4; ++u) a[u] = Pt[ti * 4 + u][k2];
        f32x2 b2 = *(const f32x2*)&St[k2][tj * 2];
        #pragma unroll
        for (int u = 0; u < 4; ++u) { acc[u][0] += a[u] * b2[0]; acc[u][1] += a[u] * b2[1]; }
      }
    }
    #pragma unroll
    for (int u = 0; u < 4; ++u) {
      Ac[(i0 + ti * 4 + u) * 256 + j0 + tj * 2] = acc[u][0];
      Ac[(i0 + ti * 4 + u) * 256 + j0 + tj * 2 + 1] = acc[u][1];
    }
  } else if (b == 32) {
    int lane = t & 63, w = t >> 6;
    f32x4 sk4 = *(const f32x4*)&sk[lane * 4];
    for (int ii = 0; ii < 64; ++ii) {
      int i = w * 64 + ii;
      f32x4 p4 = *(const f32x4*)&Pc[i * 256 + lane * 4];
      float s = p4[0] * sk4[0] + p4[1] * sk4[1] + p4[2] * sk4[2] + p4[3] * sk4[3];
      WRED(s);
      if (lane == 0) tc[i] = s;
    }
  } else {
    float s0 = 0.f, s1 = 0.f, s2 = 0.f, s3 = 0.f;
    #pragma unroll 4
    for (int i = 0; i < 256; i += 4) {
      s0 += gc[i] * S[i * 256 + t];
      s1 += gc[i + 1] * S[(i + 1) * 256 + t];
      s2 += gc[i + 2] * S[(i + 2) * 256 + t];
      s3 += gc[i + 3] * S[(i + 3) * 256 + t];
    }
    rv[t] = (s0 + s1) + (s2 + s3);
    if (t < 64) {
      f32x4 g4 = *(const f32x4*)&gc[t * 4];
      f32x4 sk4 = *(const f32x4*)&sk[t * 4];
      float a = g4[0] * sk4[0] + g4[1] * sk4[1] + g4[2] * sk4[2] + g4[3] * sk4[3];
      WRED(a);
      if (t == 0) scal[5] = a;
    }
  }
}

// partial matvecs: part[iseg*2+0][j] = sum Wv[i,j] sv[i] ; +1 -> rv   (8 isegs x 16 jblks)
__global__ __launch_bounds__(256) void k_wcc_part(
    const float* __restrict__ Wv, const float* __restrict__ sv,
    const float* __restrict__ rv, float* __restrict__ part) {
  __shared__ float red[2][2][128];
  int t = threadIdx.x;
  int jblk = blockIdx.x & 15, iseg = blockIdx.x >> 4;
  int j = jblk * 128 + (t & 127);
  int half = t >> 7;
  int ib = iseg * 32 + half * 16;
  float sw = 0.f, sc = 0.f;
  #pragma unroll
  for (int u = 0; u < 16; ++u) {
    float w = Wv[(size_t)(ib + u) * HD + j];
    sw += w * sv[ib + u];
    sc += w * rv[ib + u];
  }
  red[half][0][t & 127] = sw;
  red[half][1][t & 127] = sc;
  __syncthreads();
  if (half == 0) {
    sw += red[1][0][t & 127];
    sc += red[1][1][t & 127];
    part[(iseg * 2) * 2048 + j] = sw;
    part[(iseg * 2 + 1) * 2048 + j] = sc;
  }
}

// Gc = Ac @ Wv + tc bv^T + uc (w + N bv)^T ; also materializes cc
__global__ __launch_bounds__(256) void k_gc(
    const float* __restrict__ Ac, const float* __restrict__ Wv,
    const float* __restrict__ tc, const float* __restrict__ uc,
    const float* __restrict__ part, const float* __restrict__ bv,
    const float* __restrict__ scal, float* __restrict__ Gc, float* __restrict__ cc) {
  __shared__ float At[64][68];
  __shared__ float Bt[64][132];
  int t = threadIdx.x;
  int i0 = blockIdx.x * 64, j0 = blockIdx.y * 128;
  int ti = t >> 5, tj = t & 31;
  float acc[8][4] = {};
  for (int kt = 0; kt < 256; kt += 64) {
    __syncthreads();
    {
      int rr = t >> 2, c16 = (t & 3) * 16;
      #pragma unroll
      for (int c = 0; c < 4; ++c)
        *(f32x4*)&At[rr][c16 + c * 4] = *(const f32x4*)&Ac[(i0 + rr) * 256 + kt + c16 + c * 4];
    }
    {
      int rr = t >> 2, c32 = (t & 3) * 32;
      #pragma unroll
      for (int c = 0; c < 8; ++c)
        *(f32x4*)&Bt[rr][c32 + c * 4] = *(const f32x4*)&Wv[(size_t)(kt + rr) * HD + j0 + c32 + c * 4];
    }
    __syncthreads();
    #pragma unroll 8
    for (int k2 = 0; k2 < 64; ++k2) {
      float a[8];
      #pragma unroll
      for (int u = 0; u < 8; ++u) a[u] = At[ti * 8 + u][k2];
      f32x4 b = *(const f32x4*)&Bt[k2][tj * 4];
      #pragma unroll
      for (int u = 0; u < 8; ++u)
        #pragma unroll
        for (int v = 0; v < 4; ++v) acc[u][v] += a[u] * b[v];
    }
  }
  int j = j0 + tj * 4;
  f32x4 sw4 = {0.f, 0.f, 0.f, 0.f}, sc4 = {0.f, 0.f, 0.f, 0.f};
  #pragma unroll
  for (int p = 0; p < 8; ++p) {
    sw4 += *(const f32x4*)&part[(p * 2) * 2048 + j];
    sc4 += *(const f32x4*)&part[(p * 2 + 1) * 2048 + j];
  }
  f32x4 bv4 = *(const f32x4*)&bv[j];
  f32x4 wnb;
  #pragma unroll
  for (int v = 0; v < 4; ++v) wnb[v] = sw4[v] + 20000.0f * bv4[v];
  if (blockIdx.x == 0 && ti == 0) {
    float ac = scal[5], dc = scal[4];
    f32x4 ccv;
    #pragma unroll
    for (int v = 0; v < 4; ++v) ccv[v] = sc4[v] + ac * bv4[v] + dc * wnb[v];
    *(f32x4*)&cc[j] = ccv;
  }
  #pragma unroll
  for (int u = 0; u < 8; ++u) {
    int i = i0 + ti * 8 + u;
    float tci = tc[i], uci = uc[i];
    f32x4 o;
    #pragma unroll
    for (int v = 0; v < 4; ++v)
      o[v] = acc[u][v] + tci * bv4[v] + uci * wnb[v];
    *(f32x4*)&Gc[(size_t)i * HD + j] = o;
  }
}

// merged: [0,17) scal2 | [17,273) M = Gc Gc^T partials | [273,417) Hc partials
__global__ __launch_bounds__(256) void k_post(
    const float* __restrict__ Gc, const float* __restrict__ cc,
    const float* __restrict__ Wo, const float* __restrict__ g,
    const float* __restrict__ lnb, const float* __restrict__ scal_c,
    unsigned short* __restrict__ Bbt, float* __restrict__ M_part,
    float* __restrict__ Hc_part, float* __restrict__ scal) {
  __shared__ float SMEM[6528];
  int b = blockIdx.x, t = threadIdx.x;
  if (b < 17) {
    int lane = t & 63, w = t >> 6;
    if (b < 16) {
      int rb = b * 16 + w * 4;
      for (int q2 = 0; q2 < 4; ++q2) {
        int row = rb + q2;
        float s1 = 0.f, s2 = 0.f;
        #pragma unroll
        for (int c = 0; c < 8; ++c) {
          int kk2 = c * 256 + lane * 4;
          f32x4 g4 = *(const f32x4*)&Gc[(size_t)row * HD + kk2];
          f32x4 c4v = *(const f32x4*)&cc[kk2];
          #pragma unroll
          for (int u = 0; u < 4; ++u) { s1 += g4[u]; s2 += g4[u] * c4v[u]; }
        }
        WRED(s1); WRED(s2);
        if (lane == 0) {
          Bbt[512 * 256 + row] = f2bf(s1 * (1.0f / 2048.0f));
          Bbt[513 * 256 + row] = f2bf(s2);
        }
      }
    } else {
      float s1 = 0.f, s2 = 0.f;
      #pragma unroll
      for (int c = 0; c < 2; ++c) {
        f32x4 v = *(const f32x4*)&cc[t * 8 + c * 4];
        #pragma unroll
        for (int u = 0; u < 4; ++u) { s1 += v[u]; s2 += v[u] * v[u]; }
      }
      WRED(s1); WRED(s2);
      if (lane == 0) { SMEM[w] = s1; SMEM[4 + w] = s2; }
      __syncthreads();
      if (t == 0) {
        scal[6] = SMEM[4] + SMEM[5] + SMEM[6] + SMEM[7];
        scal[7] = (SMEM[0] + SMEM[1] + SMEM[2] + SMEM[3]) * (1.0f / 2048.0f);
      }
      for (int idx = t; idx < 14 * 256; idx += 256) Bbt[514 * 256 + idx] = 0;
    }
  } else if (b < 273) {
    float (*Gi)[68] = (float(*)[68])SMEM;
    float (*Gj)[68] = (float(*)[68])(SMEM + 32 * 68);
    int idx = b - 17;
    int bx = idx & 7, by = (idx >> 3) & 7, z = idx >> 6;
    int i0 = bx * 32, j0 = by * 32;
    int ti = t >> 4, tj = t & 15;
    float acc[2][2] = {};
    for (int kt = 0; kt < 512; kt += 64) {
      int kb = z * 512 + kt;
      __syncthreads();
      {
        int rr = t >> 3, c8 = (t & 7) * 8;
        *(f32x4*)&Gi[rr][c8] = *(const f32x4*)&Gc[(size_t)(i0 + rr) * HD + kb + c8];
        *(f32x4*)&Gi[rr][c8 + 4] = *(const f32x4*)&Gc[(size_t)(i0 + rr) * HD + kb + c8 + 4];
        *(f32x4*)&Gj[rr][c8] = *(const f32x4*)&Gc[(size_t)(j0 + rr) * HD + kb + c8];
        *(f32x4*)&Gj[rr][c8 + 4] = *(const f32x4*)&Gc[(size_t)(j0 + rr) * HD + kb + c8 + 4];
      }
      __syncthreads();
      #pragma unroll 8
      for (int k2 = 0; k2 < 64; ++k2) {
        float a0 = Gi[ti * 2][k2], a1 = Gi[ti * 2 + 1][k2];
        float b0 = Gj[tj * 2][k2], b1 = Gj[tj * 2 + 1][k2];
        acc[0][0] += a0 * b0; acc[0][1] += a0 * b1;
        acc[1][0] += a1 * b0; acc[1][1] += a1 * b1;
      }
    }
    #pragma unroll
    for (int u = 0; u < 2; ++u)
      #pragma unroll
      for (int v = 0; v < 2; ++v)
        M_part[(size_t)z * 65536 + (i0 + ti * 2 + u) * 256 + j0 + tj * 2 + v] = acc[u][v];
  } else {
    float (*At)[68] = (float(*)[68])SMEM;
    float (*Bt)[68] = (float(*)[68])(SMEM + 32 * 68);
    int idx = b - 273;
    int bx = idx % 9, rem = idx / 9, by = rem & 3, z = rem >> 2;
    int i0 = bx * 32, j0 = by * 64;
    float s2 = scal_c[2];
    int ti = t >> 5, tj = t & 31;
    float acc[4][2] = {};
    for (int kt = 0; kt < 512; kt += 64) {
      int kb = z * 512 + kt;
      __syncthreads();
      {
        int rr = t >> 3, c8 = (t & 7) * 8, gi = i0 + rr;
        #pragma unroll
        for (int h = 0; h < 8; h += 4) {
          f32x4 g4 = *(const f32x4*)&g[kb + c8 + h];
          f32x4 a;
          if (gi < 256) {
            f32x4 gg = *(const f32x4*)&Gc[(size_t)gi * HD + kb + c8 + h];
            #pragma unroll
            for (int u = 0; u < 4; ++u) a[u] = gg[u] * g4[u];
          } else if (gi == 256) {
            a = g4;
          } else if (gi == 257) {
            f32x4 c4v = *(const f32x4*)&cc[kb + c8 + h];
            #pragma unroll
            for (int u = 0; u < 4; ++u) a[u] = c4v[u] * g4[u];
          } else if (gi == 258) {
            a = *(const f32x4*)&lnb[kb + c8 + h];
          } else {
            a = (f32x4){0.f, 0.f, 0.f, 0.f};
          }
          *(f32x4*)&At[rr][c8 + h] = a;
        }
      }
      {
        int rr = t >> 2, c16 = (t & 3) * 16;
        #pragma unroll
        for (int c = 0; c < 4; ++c) {
          f32x4 bb = *(const f32x4*)&Wo[(size_t)(kb + rr) * 256 + j0 + c16 + c * 4];
          #pragma unroll
          for (int u = 0; u < 4; ++u) bb[u] *= s2;
          *(f32x4*)&Bt[rr][c16 + c * 4] = bb;
        }
      }
      __syncthreads();
      #pragma unroll 8
      for (int k2 = 0; k2 < 64; ++k2) {
        float a[4];
        #pragma unroll
        for (int u = 0; u < 4; ++u) a[u] = At[ti * 4 + u][k2];
        f32x2 b2 = *(const f32x2*)&Bt[k2][tj * 2];
        #pragma unroll
        for (int u = 0; u < 4; ++u) { acc[u][0] += a[u] * b2[0]; acc[u][1] += a[u] * b2[1]; }
      }
    }
    #pragma unroll
    for (int u = 0; u < 4; ++u) {
      Hc_part[(size_t)z * 73728 + (i0 + ti * 4 + u) * 256 + j0 + tj * 2] = acc[u][0];
      Hc_part[(size_t)z * 73728 + (i0 + ti * 4 + u) * 256 + j0 + tj * 2 + 1] = acc[u][1];
    }
  }
}

// reduce M/Hc partials -> Bbt (transposed, bf16); vectors wbar/hc/bc
__global__ __launch_bounds__(256) void k_red2(
    const float* __restrict__ M_part, const float* __restrict__ Hc_part,
    const float* __restrict__ bo, unsigned short* __restrict__ Bbt,
    float* __restrict__ wbar, float* __restrict__ hcv, float* __restrict__ bcv) {
  int bi = blockIdx.x, z2 = blockIdx.y, t = threadIdx.x;
  if (z2 == 2) {
    if (bi != 0) return;
    float s0 = 0.f, s1 = 0.f, s2 = 0.f;
    #pragma unroll
    for (int z = 0; z < 4; ++z) {
      s0 += Hc_part[(size_t)z * 73728 + 256 * 256 + t];
      s1 += Hc_part[(size_t)z * 73728 + 257 * 256 + t];
      s2 += Hc_part[(size_t)z * 73728 + 258 * 256 + t];
    }
    wbar[t] = s0; hcv[t] = s1; bcv[t] = s2 + bo[t];
    return;
  }
  __shared__ unsigned short T[64][256];
  const float* src = z2 ? Hc_part : M_part;
  const size_t sp = z2 ? 73728 : 65536;
  const int base = z2 ? 256 : 0;
  for (int ii = 0; ii < 64; ++ii) {
    int i = bi * 64 + ii;
    float s = 0.f;
    #pragma unroll
    for (int z = 0; z < 4; ++z) s += src[z * sp + i * 256 + t];
    T[ii][t] = f2bf(s);
  }
  __syncthreads();
  #pragma unroll
  for (int c = 0; c < 64; c += 8) {
    u16x8 o;
    #pragma unroll
    for (int u = 0; u < 8; ++u) o[u] = T[c + u][t];
    *(u16x8*)&Bbt[(size_t)(base + t) * 256 + bi * 64 + c] = o;
  }
}

// fused final: y|z|mu|m2 = q @ Bbt^T, then LN-stats + output epilogue
__global__ __launch_bounds__(256) void k_out(
    const float* __restrict__ q, const unsigned short* __restrict__ Bbt,
    const float* __restrict__ hcv, const float* __restrict__ wbar,
    const float* __restrict__ bcv, const float* __restrict__ scal,
    float* __restrict__ out) {
  __shared__ unsigned short As[32 * 264];
  __shared__ float sqp[2][32];
  __shared__ float muL[32], m2L[32];
  const int t = threadIdx.x, lane = t & 63, wave = t >> 6;
  const int row0 = blockIdx.x * 32;
  const int r15 = lane & 15, kg = lane >> 4;
  {
    int r = t >> 3;
    #pragma unroll
    for (int ci = 0; ci < 8; ++ci) {
      int col = ci * 32 + (t & 7) * 4;
      f32x4 v = *(const f32x4*)&q[(size_t)(row0 + r) * HIW + col];
      u16x4 o;
      #pragma unroll
      for (int u = 0; u < 4; ++u) o[u] = f2bf(v[u]);
      *(u16x4*)&As[r * 264 + col] = o;
    }
  }
  __syncthreads();
  const int wc = wave * 128;
  f32x4 acc[2][9];
  #pragma unroll
  for (int m = 0; m < 2; ++m)
    #pragma unroll
    for (int n = 0; n < 9; ++n) acc[m][n] = (f32x4){0.f, 0.f, 0.f, 0.f};
  #pragma unroll
  for (int ko = 0; ko < 8; ++ko) {
    bf16x8 af0 = *(const bf16x8*)&As[r15 * 264 + ko * 32 + kg * 8];
    bf16x8 af1 = *(const bf16x8*)&As[(16 + r15) * 264 + ko * 32 + kg * 8];
    #pragma unroll
    for (int ni = 0; ni < 9; ++ni) {
      if (ni == 8 && wave != 3) continue;
      int colb = wc + ni * 16 + r15;
      bf16x8 bfr = *(const bf16x8*)&Bbt[(size_t)colb * 256 + ko * 32 + kg * 8];
      acc[0][ni] = __builtin_amdgcn_mfma_f32_16x16x32_bf16(af0, bfr, acc[0][ni], 0, 0, 0);
      acc[1][ni] = __builtin_amdgcn_mfma_f32_16x16x32_bf16(af1, bfr, acc[1][ni], 0, 0, 0);
    }
  }
  if (wave < 2) {
    #pragma unroll
    for (int m = 0; m < 2; ++m)
      #pragma unroll
      for (int r = 0; r < 4; ++r) {
        int rowl = m * 16 + kg * 4 + r;
        float p = 0.f;
        #pragma unroll
        for (int ni = 0; ni < 8; ++ni) {
          int col = wc + ni * 16 + r15;
          p += acc[m][ni][r] * bf2f(As[rowl * 264 + col]);
        }
        p += __shfl_xor(p, 1); p += __shfl_xor(p, 2);
        p += __shfl_xor(p, 4); p += __shfl_xor(p, 8);
        if (r15 == 0) sqp[wave][rowl] = p;
      }
  }
  if (wave == 3) {
    #pragma unroll
    for (int m = 0; m < 2; ++m)
      #pragma unroll
      for (int r = 0; r < 4; ++r) {
        int rowl = m * 16 + kg * 4 + r;
        if (r15 == 0) muL[rowl] = acc[m][8][r];
        if (r15 == 1) m2L[rowl] = acc[m][8][r];
      }
  }
  __syncthreads();
  if (wave >= 2) {
    const float css = scal[6], cbar = scal[7];
    #pragma unroll
    for (int m = 0; m < 2; ++m)
      #pragma unroll
      for (int r = 0; r < 4; ++r) {
        int rowl = m * 16 + kg * 4 + r;
        float mu = muL[rowl] + cbar;
        float ss = sqp[0][rowl] + sqp[1][rowl] + 2.0f * m2L[rowl] + css;
        float var = ss * (1.0f / 2048.0f) - mu * mu;
        float rstd = rsqrtf(var + 1e-5f);
        int grow = row0 + rowl;
        #pragma unroll
        for (int ni = 0; ni < 8; ++ni) {
          int oc = (wc - 256) + ni * 16 + r15;
          float zv = acc[m][ni][r] + hcv[oc];
          out[(size_t)grow * HIW + oc] = rstd * (zv - mu * wbar[oc]) + bcv[oc];
        }
      }
  }
}

extern "C" void kernel_launch(void* const* d_in, const int* in_sizes, int n_in,
                              void* d_out, int out_size, void* d_ws, size_t ws_size,
                              hipStream_t stream) {
  const float* q   = (const float*)d_in[0];
  const float* k   = (const float*)d_in[1];
  const float* v   = (const float*)d_in[2];
  const int* layer = (const int*)d_in[3];
  const float* Wq1 = (const float*)d_in[4];  const float* bq1 = (const float*)d_in[5];
  const float* Wk1 = (const float*)d_in[6];  const float* bk1 = (const float*)d_in[7];
  const float* Wq2 = (const float*)d_in[8];  const float* bq2 = (const float*)d_in[9];
  const float* Wk2 = (const float*)d_in[10]; const float* bk2 = (const float*)d_in[11];
  const float* Wv  = (const float*)d_in[12]; const float* bv  = (const float*)d_in[13];
  const float* lng = (const float*)d_in[14]; const float* lnb = (const float*)d_in[15];
  const float* Wo  = (const float*)d_in[16]; const float* bo  = (const float*)d_in[17];
  const float* lq1 = (const float*)d_in[18]; const float* lk1 = (const float*)d_in[19];
  const float* lq2 = (const float*)d_in[20]; const float* lk2 = (const float*)d_in[21];

  char* p = (char*)d_ws;
  float* S_part = (float*)p;  p += (size_t)64 * 65536 * 4;
  float* skp = (float*)p;     p += 64 * 256 * 4;
  float* svp = (float*)p;     p += 64 * 256 * 4;
  float* Pc_part = (float*)p; p += (size_t)32 * 65536 * 4;
  float* S  = (float*)p;      p += 65536 * 4;
  float* Pc = (float*)p;      p += 65536 * 4;
  float* sk = (float*)p;      p += 1024;
  float* sv = (float*)p;      p += 1024;
  float* gc = (float*)p;      p += 1024;
  float* uc = (float*)p;      p += 1024;
  float* tc = (float*)p;      p += 1024;
  float* rv = (float*)p;      p += 1024;
  float* wcc_part = (float*)p; p += (size_t)16 * 2048 * 4;
  float* cc  = (float*)p;     p += 2048 * 4;
  float* Ac  = (float*)p;     p += 65536 * 4;
  float* Gc  = (float*)p;     p += (size_t)2048 * 256 * 4;
  float* M_part  = (float*)p; p += (size_t)4 * 65536 * 4;
  float* Hc_part = (float*)p; p += (size_t)4 * 288 * 256 * 4;
  unsigned short* Bbt = (unsigned short*)p; p += (size_t)528 * 256 * 2;
  float* wbar = (float*)p;    p += 1024;
  float* hcv  = (float*)p;    p += 1024;
  float* bcv  = (float*)p;    p += 1024;
  float* scal = (float*)p;    p += 256;

  const dim3 b256(256);
  k_front<<<dim3(385), b256, 0, stream>>>(k, v, Wq1, Wk1, Wq2, Wk2,
      lq1, lk1, lq2, lk2, bq1, bk1, bq2, bk2, layer, S_part, skp, svp, Pc_part, scal);
  k_sred<<<dim3(546), b256, 0, stream>>>(S_part, Pc_part, skp, svp, S, Pc, sk, sv,
                                         Wk1, Wk2, Wq1, Wq2, bq1, bq2, bk1, bk2, scal, gc, uc);
  k_ac<<<dim3(34), b256, 0, stream>>>(Pc, S, gc, sk, Ac, tc, rv, scal);
  k_wcc_part<<<dim3(128), b256, 0, stream>>>(Wv, sv, rv, wcc_part);
  k_gc<<<dim3(4, 16), b256, 0, stream>>>(Ac, Wv, tc, uc, wcc_part, bv, scal, Gc, cc);
  k_post<<<dim3(417), b256, 0, stream>>>(Gc, cc, Wo, lng, lnb, scal, Bbt, M_part, Hc_part, scal);
  k_red2<<<dim3(4, 3), b256, 0, stream>>>(M_part, Hc_part, bo, Bbt, wbar, hcv, bcv);
  k_out<<<dim3(625), b256, 0, stream>>>(q, Bbt, hcv, wbar, bcv, scal, (float*)d_out);
}

// Round 7
// 179.066 us; speedup vs baseline: 1.0344x; 1.0344x over previous
//
#include <hip/hip_runtime.h>
#include <stdint.h>

typedef __bf16 bf16x8 __attribute__((ext_vector_type(8)));
typedef float f32x4 __attribute__((ext_vector_type(4)));
typedef float f32x2 __attribute__((ext_vector_type(2)));
typedef unsigned short u16x4 __attribute__((ext_vector_type(4)));
typedef unsigned short u16x8 __attribute__((ext_vector_type(8)));

#define NTOK 20000
#define HIW  256
#define HD   2048
#define LDK  66     // shorts; 33 dwords (odd) -> conflict-free writes / spread b128 reads
#define BUFS 8448   // 128*66 shorts = one matrix tile buffer

static __device__ __forceinline__ unsigned short f2bf(float f) {
  union { float f; unsigned u; } c; c.f = f;
  unsigned u = c.u + (0x7fffu + ((c.u >> 16) & 1u));   // RNE
  return (unsigned short)(u >> 16);
}
static __device__ __forceinline__ float bf2f(unsigned short h) {
  union { unsigned u; float f; } c; c.u = ((unsigned)h) << 16;
  return c.f;
}

#define WRED(x) { x += __shfl_xor(x,32); x += __shfl_xor(x,16); x += __shfl_xor(x,8); \
                  x += __shfl_xor(x,4);  x += __shfl_xor(x,2);  x += __shfl_xor(x,1); }

// ============ k_front (512 thr): [0,256) k_s | [256,384) k_pc | 384 lambda ============
// scal: 0=lam 1=-lam 2=1-li 3=li 4=dc 5=alpha_c 6=css 7=cbar
__global__ __launch_bounds__(512) void k_front(
    const float* __restrict__ kk, const float* __restrict__ vv,
    const float* __restrict__ Wq1, const float* __restrict__ Wk1,
    const float* __restrict__ Wq2, const float* __restrict__ Wk2,
    const float* __restrict__ lq1, const float* __restrict__ lk1,
    const float* __restrict__ lq2, const float* __restrict__ lk2,
    const float* __restrict__ bq1, const float* __restrict__ bk1,
    const float* __restrict__ bq2, const float* __restrict__ bk2,
    const int* __restrict__ layer,
    float* __restrict__ S_part, float* __restrict__ skp, float* __restrict__ svp,
    float* __restrict__ Pc_part, float* __restrict__ scal) {
  __shared__ unsigned short SH[4 * BUFS];   // 67584 B: 2 double-buffered (A,B) tiles
  const int b = blockIdx.x;
  const int t = threadIdx.x, lane = t & 63, wave = t >> 6;
  const int wr = (wave >> 1) * 32, wc = (wave & 1) * 64;
  const int r15 = lane & 15, kg = (lane >> 4) * 8;

  if (b < 256) {
    // ----- S_part[z] = k^T v over n-chunk z; double-buffered, counted-wait barriers -----
    const int z = b & 63, by = (b >> 6) & 1, bx = (b >> 7) & 1;
    const int i0 = bx * 128, j0 = by * 128;
    const int n_lo = z * 313;
    const int cnt = (NTOK - n_lo < 313) ? (NTOK - n_lo) : 313;
    f32x4 acc[2][4];
    #pragma unroll
    for (int m = 0; m < 2; ++m)
      #pragma unroll
      for (int n = 0; n < 4; ++n) acc[m][n] = (f32x4){0.f, 0.f, 0.f, 0.f};

    const int matsel = t >> 8, col = t & 127, half = (t >> 7) & 1;
    const float* src = matsel ? vv : kk;
    const int gcol = (matsel ? j0 : i0) + col;
    unsigned short* Lb0 = SH + matsel * BUFS;              // buffer 0 (A or B half)
    unsigned short* Lb1 = SH + 2 * BUFS + matsel * BUFS;   // buffer 1
    const int tbase = half * 32;
    float csum = 0.f;
    float rA[32], rB[32];

#define LOADK(dst, KT)                                                        \
    { _Pragma("unroll")                                                       \
      for (int g = 0; g < 32; ++g) {                                          \
        int nn = (KT) * 64 + tbase + g;                                       \
        dst[g] = (nn < cnt) ? src[(size_t)(n_lo + nn) * HIW + gcol] : 0.f;    \
      } }
#define WRITEK(dstp, rr)                                                      \
    { _Pragma("unroll")                                                       \
      for (int g4 = 0; g4 < 8; ++g4) {                                        \
        u16x4 o;                                                              \
        _Pragma("unroll")                                                     \
        for (int u = 0; u < 4; ++u) {                                         \
          float x = rr[g4 * 4 + u]; csum += x; o[u] = f2bf(x);                \
        }                                                                     \
        *(u16x4*)&dstp[col * LDK + tbase + g4 * 4] = o;                       \
      } }

    LOADK(rA, 0)
    WRITEK(Lb0, rA)
    LOADK(rB, 1)
    asm volatile("s_waitcnt lgkmcnt(0)" ::: "memory");
    __builtin_amdgcn_s_barrier();

    #pragma unroll
    for (int kt = 0; kt < 5; ++kt) {
      const unsigned short* Akr = SH + (kt & 1) * 2 * BUFS;
      const unsigned short* Bkr = Akr + BUFS;
      #pragma unroll
      for (int ks = 0; ks < 2; ++ks) {
        const int ko = ks * 32 + kg;
        bf16x8 ah[2], bh[4];
        #pragma unroll
        for (int m = 0; m < 2; ++m)
          ah[m] = *(const bf16x8*)&Akr[(wr + m * 16 + r15) * LDK + ko];
        #pragma unroll
        for (int n = 0; n < 4; ++n)
          bh[n] = *(const bf16x8*)&Bkr[(wc + n * 16 + r15) * LDK + ko];
        #pragma unroll
        for (int m = 0; m < 2; ++m)
          #pragma unroll
          for (int n = 0; n < 4; ++n)
            acc[m][n] = __builtin_amdgcn_mfma_f32_16x16x32_bf16(ah[m], bh[n], acc[m][n], 0, 0, 0);
      }
      if (kt < 4) {
        unsigned short* Ld = SH + ((kt + 1) & 1) * 2 * BUFS + matsel * BUFS;
        if ((kt & 1) == 0) {
          WRITEK(Ld, rB)
          if (kt + 2 <= 4) LOADK(rA, kt + 2)
        } else {
          WRITEK(Ld, rA)
          if (kt + 2 <= 4) LOADK(rB, kt + 2)
        }
      }
      asm volatile("s_waitcnt lgkmcnt(0)" ::: "memory");
      __builtin_amdgcn_s_barrier();
    }
#undef LOADK
#undef WRITEK
    const int rg = (lane >> 4) * 4;
    #pragma unroll
    for (int m = 0; m < 2; ++m)
      #pragma unroll
      for (int n = 0; n < 4; ++n)
        #pragma unroll
        for (int r = 0; r < 4; ++r)
          S_part[(size_t)z * 65536 + (i0 + wr + m * 16 + rg + r) * 256 + (j0 + wc + n * 16 + r15)] =
              acc[m][n][r];
    if (bx == by) {
      float* red = (float*)SH;
      red[t] = csum;
      __syncthreads();
      if (t < 128)      skp[z * 256 + i0 + t]         = red[t] + red[t + 128];
      else if (t < 256) svp[z * 256 + j0 + (t - 128)] = red[t + 128] + red[t + 256];
    }
  } else if (b < 384) {
    // ----- Pc_part[pair*16+z] = Wa Wb^T K-slice (bf16, unscaled) -----
    const int idx = b - 256;
    const int pair = idx >> 6, rem = idx & 63;
    const int z = rem & 15, by = (rem >> 4) & 1, bx = (rem >> 5) & 1;
    const int i0 = bx * 128, j0 = by * 128;
    const float* Wa = pair ? Wq2 : Wq1;
    const float* Wb = pair ? Wk2 : Wk1;
    f32x4 acc[2][4];
    #pragma unroll
    for (int m = 0; m < 2; ++m)
      #pragma unroll
      for (int n = 0; n < 4; ++n) acc[m][n] = (f32x4){0.f, 0.f, 0.f, 0.f};
    unsigned short* Ak = SH;
    unsigned short* Bk = SH + BUFS;
    const int srow = t >> 2, sq = (t & 3) * 16;
    for (int kt = 0; kt < 2; ++kt) {
      const int kb = z * 128 + kt * 64 + sq;
      __syncthreads();
      #pragma unroll
      for (int c = 0; c < 4; ++c) {
        f32x4 a = *(const f32x4*)&Wa[(size_t)(i0 + srow) * HD + kb + c * 4];
        f32x4 bb = *(const f32x4*)&Wb[(size_t)(j0 + srow) * HD + kb + c * 4];
        u16x4 oa, ob;
        #pragma unroll
        for (int u = 0; u < 4; ++u) { oa[u] = f2bf(a[u]); ob[u] = f2bf(bb[u]); }
        *(u16x4*)&Ak[srow * LDK + sq + c * 4] = oa;
        *(u16x4*)&Bk[srow * LDK + sq + c * 4] = ob;
      }
      __syncthreads();
      #pragma unroll
      for (int ks = 0; ks < 2; ++ks) {
        const int ko = ks * 32 + kg;
        bf16x8 ah[2], bh[4];
        #pragma unroll
        for (int m = 0; m < 2; ++m)
          ah[m] = *(const bf16x8*)&Ak[(wr + m * 16 + r15) * LDK + ko];
        #pragma unroll
        for (int n = 0; n < 4; ++n)
          bh[n] = *(const bf16x8*)&Bk[(wc + n * 16 + r15) * LDK + ko];
        #pragma unroll
        for (int m = 0; m < 2; ++m)
          #pragma unroll
          for (int n = 0; n < 4; ++n)
            acc[m][n] = __builtin_amdgcn_mfma_f32_16x16x32_bf16(ah[m], bh[n], acc[m][n], 0, 0, 0);
      }
    }
    const int rg = (lane >> 4) * 4;
    #pragma unroll
    for (int m = 0; m < 2; ++m)
      #pragma unroll
      for (int n = 0; n < 4; ++n)
        #pragma unroll
        for (int r = 0; r < 4; ++r)
          Pc_part[(size_t)(pair * 16 + z) * 65536 +
                  (i0 + wr + m * 16 + rg + r) * 256 + (j0 + wc + n * 16 + r15)] = acc[m][n][r];
  } else {
    // ----- lambda scalars (first 256 threads) -----
    float* red = (float*)SH;
    if (t < 256) {
      float p1 = lq1[t] * lk1[t], p2 = lq2[t] * lk2[t];
      float d1 = 0.f, d2 = 0.f;
      #pragma unroll
      for (int u = 0; u < 8; ++u) {
        d1 += bq1[t * 8 + u] * bk1[t * 8 + u];
        d2 += bq2[t * 8 + u] * bk2[t * 8 + u];
      }
      WRED(p1); WRED(p2); WRED(d1); WRED(d2);
      int w = t >> 6;
      if ((t & 63) == 0) { red[w] = p1; red[4 + w] = p2; red[8 + w] = d1; red[12 + w] = d2; }
    }
    __syncthreads();
    if (t == 0) {
      float s1 = red[0] + red[1] + red[2] + red[3];
      float s2 = red[4] + red[5] + red[6] + red[7];
      float dd1 = red[8] + red[9] + red[10] + red[11];
      float dd2 = red[12] + red[13] + red[14] + red[15];
      float li = 0.8f - 0.6f * expf(-0.3f * (float)layer[0]);
      float lam = expf(s1) - expf(s2) + li;
      scal[0] = lam; scal[1] = -lam; scal[2] = 1.0f - li; scal[3] = li;
      scal[4] = dd1 - lam * dd2;
    }
  }
}

// reductions (f32x4) + gc/uc matvecs
__global__ __launch_bounds__(256) void k_sred(
    const float* __restrict__ S_part, const float* __restrict__ Pc_part,
    const float* __restrict__ skp, const float* __restrict__ svp,
    float* __restrict__ S, float* __restrict__ Pc,
    float* __restrict__ sk, float* __restrict__ sv,
    const float* __restrict__ Wk1, const float* __restrict__ Wk2,
    const float* __restrict__ Wq1, const float* __restrict__ Wq2,
    const float* __restrict__ bq1, const float* __restrict__ bq2,
    const float* __restrict__ bk1, const float* __restrict__ bk2,
    const float* __restrict__ scal, float* __restrict__ gc, float* __restrict__ uc) {
  int b = blockIdx.x, t = threadIdx.x;
  if (b < 64) {
    size_t idx = (size_t)b * 1024 + t * 4;
    f32x4 s0 = {0.f, 0.f, 0.f, 0.f}, s1 = {0.f, 0.f, 0.f, 0.f};
    #pragma unroll 4
    for (int z = 0; z < 64; z += 2) {
      s0 += *(const f32x4*)&S_part[(size_t)z * 65536 + idx];
      s1 += *(const f32x4*)&S_part[(size_t)(z + 1) * 65536 + idx];
    }
    *(f32x4*)&S[idx] = s0 + s1;
  } else if (b < 128) {
    size_t idx = (size_t)(b - 64) * 1024 + t * 4;
    f32x4 s1 = {0.f, 0.f, 0.f, 0.f}, s2 = {0.f, 0.f, 0.f, 0.f};
    #pragma unroll
    for (int z = 0; z < 16; ++z) {
      s1 += *(const f32x4*)&Pc_part[(size_t)z * 65536 + idx];
      s2 += *(const f32x4*)&Pc_part[(size_t)(16 + z) * 65536 + idx];
    }
    float lam = scal[0];
    f32x4 o;
    #pragma unroll
    for (int u = 0; u < 4; ++u) o[u] = s1[u] - lam * s2[u];
    *(f32x4*)&Pc[idx] = o;
  } else if (b < 130) {
    const float* src = (b == 128) ? skp : svp;
    float s = 0.f;
    for (int z = 0; z < 64; ++z) s += src[z * 256 + t];
    if (b == 128) sk[t] = s; else sv[t] = s;
  } else {
    int bb = b - 130, lane = t & 63, w = t >> 6;
    bool dogc = bb < 16;
    const float* A1 = dogc ? Wk1 : Wq1;
    const float* A2 = dogc ? Wk2 : Wq2;
    const float* x1 = dogc ? bq1 : bk1;
    const float* x2 = dogc ? bq2 : bk2;
    float* outv = dogc ? gc : uc;
    float lam = scal[0];
    int rb = (bb & 15) * 16 + w * 4;
    for (int q2 = 0; q2 < 4; ++q2) {
      int row = rb + q2;
      float s1 = 0.f, s2 = 0.f;
      #pragma unroll
      for (int c = 0; c < 8; ++c) {
        int kk2 = c * 256 + lane * 4;
        f32x4 a1 = *(const f32x4*)&A1[(size_t)row * HD + kk2];
        f32x4 a2 = *(const f32x4*)&A2[(size_t)row * HD + kk2];
        f32x4 v1 = *(const f32x4*)&x1[kk2];
        f32x4 v2 = *(const f32x4*)&x2[kk2];
        #pragma unroll
        for (int u = 0; u < 4; ++u) { s1 += a1[u] * v1[u]; s2 += a2[u] * v2[u]; }
      }
      WRED(s1); WRED(s2);
      if (lane == 0) outv[row] = s1 - lam * s2;
    }
  }
}

// Ac = Pc @ S ; tc = Pc @ sk ; rv = S^T gc ; alpha_c = gc . sk
__global__ __launch_bounds__(256) void k_ac(
    const float* __restrict__ Pc, const float* __restrict__ S,
    const float* __restrict__ gc, const float* __restrict__ sk,
    float* __restrict__ Ac, float* __restrict__ tc, float* __restrict__ rv,
    float* __restrict__ scal) {
  int b = blockIdx.x, t = threadIdx.x;
  if (b < 32) {
    __shared__ float Pt[32][68];
    __shared__ float St[64][68];
    int i0 = (b >> 2) * 32, j0 = (b & 3) * 64;
    int ti = t >> 5, tj = t & 31;
    float acc[4][2] = {};
    for (int kt = 0; kt < 256; kt += 64) {
      __syncthreads();
      {
        int rr = t >> 3, c8 = (t & 7) * 8;
        *(f32x4*)&Pt[rr][c8] = *(const f32x4*)&Pc[(i0 + rr) * 256 + kt + c8];
        *(f32x4*)&Pt[rr][c8 + 4] = *(const f32x4*)&Pc[(i0 + rr) * 256 + kt + c8 + 4];
      }
      {
        int rr = t >> 2, c16 = (t & 3) * 16;
        #pragma unroll
        for (int c = 0; c < 4; ++c)
          *(f32x4*)&St[rr][c16 + c * 4] = *(const f32x4*)&S[(kt + rr) * 256 + j0 + c16 + c * 4];
      }
      __syncthreads();
      #pragma unroll 8
      for (int k2 = 0; k2 < 64; ++k2) {
        float a[4];
        #pragma unroll
        for (int u = 0; u < 4; ++u) a[u] = Pt[ti * 4 + u][k2];
        f32x2 b2 = *(const f32x2*)&St[k2][tj * 2];
        #pragma unroll
        for (int u = 0; u < 4; ++u) { acc[u][0] += a[u] * b2[0]; acc[u][1] += a[u] * b2[1]; }
      }
    }
    #pragma unroll
    for (int u = 0; u < 4; ++u) {
      Ac[(i0 + ti * 4 + u) * 256 + j0 + tj * 2] = acc[u][0];
      Ac[(i0 + ti * 4 + u) * 256 + j0 + tj * 2 + 1] = acc[u][1];
    }
  } else if (b == 32) {
    int lane = t & 63, w = t >> 6;
    f32x4 sk4 = *(const f32x4*)&sk[lane * 4];
    for (int ii = 0; ii < 64; ++ii) {
      int i = w * 64 + ii;
      f32x4 p4 = *(const f32x4*)&Pc[i * 256 + lane * 4];
      float s = p4[0] * sk4[0] + p4[1] * sk4[1] + p4[2] * sk4[2] + p4[3] * sk4[3];
      WRED(s);
      if (lane == 0) tc[i] = s;
    }
  } else {
    float s0 = 0.f, s1 = 0.f, s2 = 0.f, s3 = 0.f;
    #pragma unroll 4
    for (int i = 0; i < 256; i += 4) {
      s0 += gc[i] * S[i * 256 + t];
      s1 += gc[i + 1] * S[(i + 1) * 256 + t];
      s2 += gc[i + 2] * S[(i + 2) * 256 + t];
      s3 += gc[i + 3] * S[(i + 3) * 256 + t];
    }
    rv[t] = (s0 + s1) + (s2 + s3);
    if (t < 64) {
      f32x4 g4 = *(const f32x4*)&gc[t * 4];
      f32x4 sk4 = *(const f32x4*)&sk[t * 4];
      float a = g4[0] * sk4[0] + g4[1] * sk4[1] + g4[2] * sk4[2] + g4[3] * sk4[3];
      WRED(a);
      if (t == 0) scal[5] = a;
    }
  }
}

// partial matvecs: part[iseg*2+0][j] = sum Wv[i,j] sv[i] ; +1 -> rv   (8 isegs x 16 jblks)
__global__ __launch_bounds__(256) void k_wcc_part(
    const float* __restrict__ Wv, const float* __restrict__ sv,
    const float* __restrict__ rv, float* __restrict__ part) {
  __shared__ float red[2][2][128];
  int t = threadIdx.x;
  int jblk = blockIdx.x & 15, iseg = blockIdx.x >> 4;
  int j = jblk * 128 + (t & 127);
  int half = t >> 7;
  int ib = iseg * 32 + half * 16;
  float sw = 0.f, sc = 0.f;
  #pragma unroll
  for (int u = 0; u < 16; ++u) {
    float w = Wv[(size_t)(ib + u) * HD + j];
    sw += w * sv[ib + u];
    sc += w * rv[ib + u];
  }
  red[half][0][t & 127] = sw;
  red[half][1][t & 127] = sc;
  __syncthreads();
  if (half == 0) {
    sw += red[1][0][t & 127];
    sc += red[1][1][t & 127];
    part[(iseg * 2) * 2048 + j] = sw;
    part[(iseg * 2 + 1) * 2048 + j] = sc;
  }
}

// Gc = Ac @ Wv + tc bv^T + uc (w + N bv)^T ; also materializes cc
__global__ __launch_bounds__(256) void k_gc(
    const float* __restrict__ Ac, const float* __restrict__ Wv,
    const float* __restrict__ tc, const float* __restrict__ uc,
    const float* __restrict__ part, const float* __restrict__ bv,
    const float* __restrict__ scal, float* __restrict__ Gc, float* __restrict__ cc) {
  __shared__ float At[64][68];
  __shared__ float Bt[64][132];
  int t = threadIdx.x;
  int i0 = blockIdx.x * 64, j0 = blockIdx.y * 128;
  int ti = t >> 5, tj = t & 31;
  float acc[8][4] = {};
  for (int kt = 0; kt < 256; kt += 64) {
    __syncthreads();
    {
      int rr = t >> 2, c16 = (t & 3) * 16;
      #pragma unroll
      for (int c = 0; c < 4; ++c)
        *(f32x4*)&At[rr][c16 + c * 4] = *(const f32x4*)&Ac[(i0 + rr) * 256 + kt + c16 + c * 4];
    }
    {
      int rr = t >> 2, c32 = (t & 3) * 32;
      #pragma unroll
      for (int c = 0; c < 8; ++c)
        *(f32x4*)&Bt[rr][c32 + c * 4] = *(const f32x4*)&Wv[(size_t)(kt + rr) * HD + j0 + c32 + c * 4];
    }
    __syncthreads();
    #pragma unroll 8
    for (int k2 = 0; k2 < 64; ++k2) {
      float a[8];
      #pragma unroll
      for (int u = 0; u < 8; ++u) a[u] = At[ti * 8 + u][k2];
      f32x4 b = *(const f32x4*)&Bt[k2][tj * 4];
      #pragma unroll
      for (int u = 0; u < 8; ++u)
        #pragma unroll
        for (int v = 0; v < 4; ++v) acc[u][v] += a[u] * b[v];
    }
  }
  int j = j0 + tj * 4;
  f32x4 sw4 = {0.f, 0.f, 0.f, 0.f}, sc4 = {0.f, 0.f, 0.f, 0.f};
  #pragma unroll
  for (int p = 0; p < 8; ++p) {
    sw4 += *(const f32x4*)&part[(p * 2) * 2048 + j];
    sc4 += *(const f32x4*)&part[(p * 2 + 1) * 2048 + j];
  }
  f32x4 bv4 = *(const f32x4*)&bv[j];
  f32x4 wnb;
  #pragma unroll
  for (int v = 0; v < 4; ++v) wnb[v] = sw4[v] + 20000.0f * bv4[v];
  if (blockIdx.x == 0 && ti == 0) {
    float ac = scal[5], dc = scal[4];
    f32x4 ccv;
    #pragma unroll
    for (int v = 0; v < 4; ++v) ccv[v] = sc4[v] + ac * bv4[v] + dc * wnb[v];
    *(f32x4*)&cc[j] = ccv;
  }
  #pragma unroll
  for (int u = 0; u < 8; ++u) {
    int i = i0 + ti * 8 + u;
    float tci = tc[i], uci = uc[i];
    f32x4 o;
    #pragma unroll
    for (int v = 0; v < 4; ++v)
      o[v] = acc[u][v] + tci * bv4[v] + uci * wnb[v];
    *(f32x4*)&Gc[(size_t)i * HD + j] = o;
  }
}

// merged: [0,17) scal2 | [17,273) M = Gc Gc^T partials | [273,417) Hc partials
__global__ __launch_bounds__(256) void k_post(
    const float* __restrict__ Gc, const float* __restrict__ cc,
    const float* __restrict__ Wo, const float* __restrict__ g,
    const float* __restrict__ lnb, const float* __restrict__ scal_c,
    unsigned short* __restrict__ Bbt, float* __restrict__ M_part,
    float* __restrict__ Hc_part, float* __restrict__ scal) {
  __shared__ float SMEM[6528];
  int b = blockIdx.x, t = threadIdx.x;
  if (b < 17) {
    int lane = t & 63, w = t >> 6;
    if (b < 16) {
      int rb = b * 16 + w * 4;
      for (int q2 = 0; q2 < 4; ++q2) {
        int row = rb + q2;
        float s1 = 0.f, s2 = 0.f;
        #pragma unroll
        for (int c = 0; c < 8; ++c) {
          int kk2 = c * 256 + lane * 4;
          f32x4 g4 = *(const f32x4*)&Gc[(size_t)row * HD + kk2];
          f32x4 c4v = *(const f32x4*)&cc[kk2];
          #pragma unroll
          for (int u = 0; u < 4; ++u) { s1 += g4[u]; s2 += g4[u] * c4v[u]; }
        }
        WRED(s1); WRED(s2);
        if (lane == 0) {
          Bbt[512 * 256 + row] = f2bf(s1 * (1.0f / 2048.0f));
          Bbt[513 * 256 + row] = f2bf(s2);
        }
      }
    } else {
      float s1 = 0.f, s2 = 0.f;
      #pragma unroll
      for (int c = 0; c < 2; ++c) {
        f32x4 v = *(const f32x4*)&cc[t * 8 + c * 4];
        #pragma unroll
        for (int u = 0; u < 4; ++u) { s1 += v[u]; s2 += v[u] * v[u]; }
      }
      WRED(s1); WRED(s2);
      if (lane == 0) { SMEM[w] = s1; SMEM[4 + w] = s2; }
      __syncthreads();
      if (t == 0) {
        scal[6] = SMEM[4] + SMEM[5] + SMEM[6] + SMEM[7];
        scal[7] = (SMEM[0] + SMEM[1] + SMEM[2] + SMEM[3]) * (1.0f / 2048.0f);
      }
      for (int idx = t; idx < 14 * 256; idx += 256) Bbt[514 * 256 + idx] = 0;
    }
  } else if (b < 273) {
    float (*Gi)[68] = (float(*)[68])SMEM;
    float (*Gj)[68] = (float(*)[68])(SMEM + 32 * 68);
    int idx = b - 17;
    int bx = idx & 7, by = (idx >> 3) & 7, z = idx >> 6;
    int i0 = bx * 32, j0 = by * 32;
    int ti = t >> 4, tj = t & 15;
    float acc[2][2] = {};
    for (int kt = 0; kt < 512; kt += 64) {
      int kb = z * 512 + kt;
      __syncthreads();
      {
        int rr = t >> 3, c8 = (t & 7) * 8;
        *(f32x4*)&Gi[rr][c8] = *(const f32x4*)&Gc[(size_t)(i0 + rr) * HD + kb + c8];
        *(f32x4*)&Gi[rr][c8 + 4] = *(const f32x4*)&Gc[(size_t)(i0 + rr) * HD + kb + c8 + 4];
        *(f32x4*)&Gj[rr][c8] = *(const f32x4*)&Gc[(size_t)(j0 + rr) * HD + kb + c8];
        *(f32x4*)&Gj[rr][c8 + 4] = *(const f32x4*)&Gc[(size_t)(j0 + rr) * HD + kb + c8 + 4];
      }
      __syncthreads();
      #pragma unroll 8
      for (int k2 = 0; k2 < 64; ++k2) {
        float a0 = Gi[ti * 2][k2], a1 = Gi[ti * 2 + 1][k2];
        float b0 = Gj[tj * 2][k2], b1 = Gj[tj * 2 + 1][k2];
        acc[0][0] += a0 * b0; acc[0][1] += a0 * b1;
        acc[1][0] += a1 * b0; acc[1][1] += a1 * b1;
      }
    }
    #pragma unroll
    for (int u = 0; u < 2; ++u)
      #pragma unroll
      for (int v = 0; v < 2; ++v)
        M_part[(size_t)z * 65536 + (i0 + ti * 2 + u) * 256 + j0 + tj * 2 + v] = acc[u][v];
  } else {
    float (*At)[68] = (float(*)[68])SMEM;
    float (*Bt)[68] = (float(*)[68])(SMEM + 32 * 68);
    int idx = b - 273;
    int bx = idx % 9, rem = idx / 9, by = rem & 3, z = rem >> 2;
    int i0 = bx * 32, j0 = by * 64;
    float s2 = scal_c[2];
    int ti = t >> 5, tj = t & 31;
    float acc[4][2] = {};
    for (int kt = 0; kt < 512; kt += 64) {
      int kb = z * 512 + kt;
      __syncthreads();
      {
        int rr = t >> 3, c8 = (t & 7) * 8, gi = i0 + rr;
        #pragma unroll
        for (int h = 0; h < 8; h += 4) {
          f32x4 g4 = *(const f32x4*)&g[kb + c8 + h];
          f32x4 a;
          if (gi < 256) {
            f32x4 gg = *(const f32x4*)&Gc[(size_t)gi * HD + kb + c8 + h];
            #pragma unroll
            for (int u = 0; u < 4; ++u) a[u] = gg[u] * g4[u];
          } else if (gi == 256) {
            a = g4;
          } else if (gi == 257) {
            f32x4 c4v = *(const f32x4*)&cc[kb + c8 + h];
            #pragma unroll
            for (int u = 0; u < 4; ++u) a[u] = c4v[u] * g4[u];
          } else if (gi == 258) {
            a = *(const f32x4*)&lnb[kb + c8 + h];
          } else {
            a = (f32x4){0.f, 0.f, 0.f, 0.f};
          }
          *(f32x4*)&At[rr][c8 + h] = a;
        }
      }
      {
        int rr = t >> 2, c16 = (t & 3) * 16;
        #pragma unroll
        for (int c = 0; c < 4; ++c) {
          f32x4 bb = *(const f32x4*)&Wo[(size_t)(kb + rr) * 256 + j0 + c16 + c * 4];
          #pragma unroll
          for (int u = 0; u < 4; ++u) bb[u] *= s2;
          *(f32x4*)&Bt[rr][c16 + c * 4] = bb;
        }
      }
      __syncthreads();
      #pragma unroll 8
      for (int k2 = 0; k2 < 64; ++k2) {
        float a[4];
        #pragma unroll
        for (int u = 0; u < 4; ++u) a[u] = At[ti * 4 + u][k2];
        f32x2 b2 = *(const f32x2*)&Bt[k2][tj * 2];
        #pragma unroll
        for (int u = 0; u < 4; ++u) { acc[u][0] += a[u] * b2[0]; acc[u][1] += a[u] * b2[1]; }
      }
    }
    #pragma unroll
    for (int u = 0; u < 4; ++u) {
      Hc_part[(size_t)z * 73728 + (i0 + ti * 4 + u) * 256 + j0 + tj * 2] = acc[u][0];
      Hc_part[(size_t)z * 73728 + (i0 + ti * 4 + u) * 256 + j0 + tj * 2 + 1] = acc[u][1];
    }
  }
}

// reduce M/Hc partials -> Bbt (transposed, bf16); vectors wbar/hc/bc
__global__ __launch_bounds__(256) void k_red2(
    const float* __restrict__ M_part, const float* __restrict__ Hc_part,
    const float* __restrict__ bo, unsigned short* __restrict__ Bbt,
    float* __restrict__ wbar, float* __restrict__ hcv, float* __restrict__ bcv) {
  int bi = blockIdx.x, z2 = blockIdx.y, t = threadIdx.x;
  if (z2 == 2) {
    if (bi != 0) return;
    float s0 = 0.f, s1 = 0.f, s2 = 0.f;
    #pragma unroll
    for (int z = 0; z < 4; ++z) {
      s0 += Hc_part[(size_t)z * 73728 + 256 * 256 + t];
      s1 += Hc_part[(size_t)z * 73728 + 257 * 256 + t];
      s2 += Hc_part[(size_t)z * 73728 + 258 * 256 + t];
    }
    wbar[t] = s0; hcv[t] = s1; bcv[t] = s2 + bo[t];
    return;
  }
  __shared__ unsigned short T[64][256];
  const float* src = z2 ? Hc_part : M_part;
  const size_t sp = z2 ? 73728 : 65536;
  const int base = z2 ? 256 : 0;
  for (int ii = 0; ii < 64; ++ii) {
    int i = bi * 64 + ii;
    float s = 0.f;
    #pragma unroll
    for (int z = 0; z < 4; ++z) s += src[z * sp + i * 256 + t];
    T[ii][t] = f2bf(s);
  }
  __syncthreads();
  #pragma unroll
  for (int c = 0; c < 64; c += 8) {
    u16x8 o;
    #pragma unroll
    for (int u = 0; u < 8; ++u) o[u] = T[c + u][t];
    *(u16x8*)&Bbt[(size_t)(base + t) * 256 + bi * 64 + c] = o;
  }
}

// fused final: y|z|mu|m2 = q @ Bbt^T, then LN-stats + output epilogue
__global__ __launch_bounds__(256) void k_out(
    const float* __restrict__ q, const unsigned short* __restrict__ Bbt,
    const float* __restrict__ hcv, const float* __restrict__ wbar,
    const float* __restrict__ bcv, const float* __restrict__ scal,
    float* __restrict__ out) {
  __shared__ unsigned short As[32 * 264];
  __shared__ float sqp[2][32];
  __shared__ float muL[32], m2L[32];
  const int t = threadIdx.x, lane = t & 63, wave = t >> 6;
  const int row0 = blockIdx.x * 32;
  const int r15 = lane & 15, kg = lane >> 4;
  {
    int r = t >> 3;
    #pragma unroll
    for (int ci = 0; ci < 8; ++ci) {
      int col = ci * 32 + (t & 7) * 4;
      f32x4 v = *(const f32x4*)&q[(size_t)(row0 + r) * HIW + col];
      u16x4 o;
      #pragma unroll
      for (int u = 0; u < 4; ++u) o[u] = f2bf(v[u]);
      *(u16x4*)&As[r * 264 + col] = o;
    }
  }
  __syncthreads();
  const int wc = wave * 128;
  f32x4 acc[2][9];
  #pragma unroll
  for (int m = 0; m < 2; ++m)
    #pragma unroll
    for (int n = 0; n < 9; ++n) acc[m][n] = (f32x4){0.f, 0.f, 0.f, 0.f};
  #pragma unroll
  for (int ko = 0; ko < 8; ++ko) {
    bf16x8 af0 = *(const bf16x8*)&As[r15 * 264 + ko * 32 + kg * 8];
    bf16x8 af1 = *(const bf16x8*)&As[(16 + r15) * 264 + ko * 32 + kg * 8];
    #pragma unroll
    for (int ni = 0; ni < 9; ++ni) {
      if (ni == 8 && wave != 3) continue;
      int colb = wc + ni * 16 + r15;
      bf16x8 bfr = *(const bf16x8*)&Bbt[(size_t)colb * 256 + ko * 32 + kg * 8];
      acc[0][ni] = __builtin_amdgcn_mfma_f32_16x16x32_bf16(af0, bfr, acc[0][ni], 0, 0, 0);
      acc[1][ni] = __builtin_amdgcn_mfma_f32_16x16x32_bf16(af1, bfr, acc[1][ni], 0, 0, 0);
    }
  }
  if (wave < 2) {
    #pragma unroll
    for (int m = 0; m < 2; ++m)
      #pragma unroll
      for (int r = 0; r < 4; ++r) {
        int rowl = m * 16 + kg * 4 + r;
        float p = 0.f;
        #pragma unroll
        for (int ni = 0; ni < 8; ++ni) {
          int col = wc + ni * 16 + r15;
          p += acc[m][ni][r] * bf2f(As[rowl * 264 + col]);
        }
        p += __shfl_xor(p, 1); p += __shfl_xor(p, 2);
        p += __shfl_xor(p, 4); p += __shfl_xor(p, 8);
        if (r15 == 0) sqp[wave][rowl] = p;
      }
  }
  if (wave == 3) {
    #pragma unroll
    for (int m = 0; m < 2; ++m)
      #pragma unroll
      for (int r = 0; r < 4; ++r) {
        int rowl = m * 16 + kg * 4 + r;
        if (r15 == 0) muL[rowl] = acc[m][8][r];
        if (r15 == 1) m2L[rowl] = acc[m][8][r];
      }
  }
  __syncthreads();
  if (wave >= 2) {
    const float css = scal[6], cbar = scal[7];
    #pragma unroll
    for (int m = 0; m < 2; ++m)
      #pragma unroll
      for (int r = 0; r < 4; ++r) {
        int rowl = m * 16 + kg * 4 + r;
        float mu = muL[rowl] + cbar;
        float ss = sqp[0][rowl] + sqp[1][rowl] + 2.0f * m2L[rowl] + css;
        float var = ss * (1.0f / 2048.0f) - mu * mu;
        float rstd = rsqrtf(var + 1e-5f);
        int grow = row0 + rowl;
        #pragma unroll
        for (int ni = 0; ni < 8; ++ni) {
          int oc = (wc - 256) + ni * 16 + r15;
          float zv = acc[m][ni][r] + hcv[oc];
          out[(size_t)grow * HIW + oc] = rstd * (zv - mu * wbar[oc]) + bcv[oc];
        }
      }
  }
}

extern "C" void kernel_launch(void* const* d_in, const int* in_sizes, int n_in,
                              void* d_out, int out_size, void* d_ws, size_t ws_size,
                              hipStream_t stream) {
  const float* q   = (const float*)d_in[0];
  const float* k   = (const float*)d_in[1];
  const float* v   = (const float*)d_in[2];
  const int* layer = (const int*)d_in[3];
  const float* Wq1 = (const float*)d_in[4];  const float* bq1 = (const float*)d_in[5];
  const float* Wk1 = (const float*)d_in[6];  const float* bk1 = (const float*)d_in[7];
  const float* Wq2 = (const float*)d_in[8];  const float* bq2 = (const float*)d_in[9];
  const float* Wk2 = (const float*)d_in[10]; const float* bk2 = (const float*)d_in[11];
  const float* Wv  = (const float*)d_in[12]; const float* bv  = (const float*)d_in[13];
  const float* lng = (const float*)d_in[14]; const float* lnb = (const float*)d_in[15];
  const float* Wo  = (const float*)d_in[16]; const float* bo  = (const float*)d_in[17];
  const float* lq1 = (const float*)d_in[18]; const float* lk1 = (const float*)d_in[19];
  const float* lq2 = (const float*)d_in[20]; const float* lk2 = (const float*)d_in[21];

  char* p = (char*)d_ws;
  float* S_part = (float*)p;  p += (size_t)64 * 65536 * 4;
  float* skp = (float*)p;     p += 64 * 256 * 4;
  float* svp = (float*)p;     p += 64 * 256 * 4;
  float* Pc_part = (float*)p; p += (size_t)32 * 65536 * 4;
  float* S  = (float*)p;      p += 65536 * 4;
  float* Pc = (float*)p;      p += 65536 * 4;
  float* sk = (float*)p;      p += 1024;
  float* sv = (float*)p;      p += 1024;
  float* gc = (float*)p;      p += 1024;
  float* uc = (float*)p;      p += 1024;
  float* tc = (float*)p;      p += 1024;
  float* rv = (float*)p;      p += 1024;
  float* wcc_part = (float*)p; p += (size_t)16 * 2048 * 4;
  float* cc  = (float*)p;     p += 2048 * 4;
  float* Ac  = (float*)p;     p += 65536 * 4;
  float* Gc  = (float*)p;     p += (size_t)2048 * 256 * 4;
  float* M_part  = (float*)p; p += (size_t)4 * 65536 * 4;
  float* Hc_part = (float*)p; p += (size_t)4 * 288 * 256 * 4;
  unsigned short* Bbt = (unsigned short*)p; p += (size_t)528 * 256 * 2;
  float* wbar = (float*)p;    p += 1024;
  float* hcv  = (float*)p;    p += 1024;
  float* bcv  = (float*)p;    p += 1024;
  float* scal = (float*)p;    p += 256;

  const dim3 b256(256);
  k_front<<<dim3(385), dim3(512), 0, stream>>>(k, v, Wq1, Wk1, Wq2, Wk2,
      lq1, lk1, lq2, lk2, bq1, bk1, bq2, bk2, layer, S_part, skp, svp, Pc_part, scal);
  k_sred<<<dim3(162), b256, 0, stream>>>(S_part, Pc_part, skp, svp, S, Pc, sk, sv,
                                         Wk1, Wk2, Wq1, Wq2, bq1, bq2, bk1, bk2, scal, gc, uc);
  k_ac<<<dim3(34), b256, 0, stream>>>(Pc, S, gc, sk, Ac, tc, rv, scal);
  k_wcc_part<<<dim3(128), b256, 0, stream>>>(Wv, sv, rv, wcc_part);
  k_gc<<<dim3(4, 16), b256, 0, stream>>>(Ac, Wv, tc, uc, wcc_part, bv, scal, Gc, cc);
  k_post<<<dim3(417), b256, 0, stream>>>(Gc, cc, Wo, lng, lnb, scal, Bbt, M_part, Hc_part, scal);
  k_red2<<<dim3(4, 3), b256, 0, stream>>>(M_part, Hc_part, bo, Bbt, wbar, hcv, bcv);
  k_out<<<dim3(625), b256, 0, stream>>>(q, Bbt, hcv, wbar, bcv, scal, (float*)d_out);
}